// Round 9
// baseline (605.445 us; speedup 1.0000x reference)
//
#include <hip/hip_runtime.h>
#include <hip/hip_bf16.h>
#include <stdint.h>

typedef unsigned short u16;
typedef __attribute__((ext_vector_type(8))) short short8;
typedef __attribute__((ext_vector_type(4))) float f32x4;

#define DIM 128
#define CAP 64   // per-node bucket capacity; deg ~ Poisson(16), P(deg>=64) ~ 2e-18/node

__device__ __forceinline__ float bflo(uint32_t v) {
    uint32_t b = v << 16;
    float f; __builtin_memcpy(&f, &b, 4); return f;
}
__device__ __forceinline__ float bfhi(uint32_t v) {
    uint32_t b = v & 0xffff0000u;
    float f; __builtin_memcpy(&f, &b, 4); return f;
}
__device__ __forceinline__ u16 f2bf(float f) {
    uint32_t x; __builtin_memcpy(&x, &f, 4);
    uint32_t r = (x + 0x7fffu + ((x >> 16) & 1u)) >> 16;
    return (u16)r;
}
__device__ __forceinline__ uint32_t pack2bf(float a, float b) {
    return (uint32_t)f2bf(a) | ((uint32_t)f2bf(b) << 16);
}

// ---------------- sort-based CSR build (no per-edge global atomics) ----------------

__global__ __launch_bounds__(256) void k_bin1(
    const int* __restrict__ src, const int* __restrict__ dst,
    uint32_t* __restrict__ gCur, uint32_t* __restrict__ groupBuf,
    int E, int ngrp, int gcap)
{
    __shared__ uint32_t hcnt[512];
    __shared__ uint32_t hbase[512];
    __shared__ uint32_t hcur[512];
    int nb = gridDim.x;
    int per = (E + nb - 1) / nb;
    int lo = blockIdx.x * per;
    int hi = lo + per; if (hi > E) hi = E;

    for (int t = threadIdx.x; t < ngrp; t += 256) { hcnt[t] = 0; hcur[t] = 0; }
    __syncthreads();

    for (int i = lo + threadIdx.x; i < hi; i += 256)
        atomicAdd(&hcnt[((uint32_t)dst[i]) >> 8], 1u);
    __syncthreads();

    int rot = (blockIdx.x * 37) % (ngrp > 0 ? ngrp : 1);
    for (int k = threadIdx.x; k < ngrp; k += 256) {
        int t = k + rot; if (t >= ngrp) t -= ngrp;
        uint32_t c = hcnt[t];
        hbase[t] = c ? atomicAdd(&gCur[t], c) : 0u;
    }
    __syncthreads();

    for (int i = lo + threadIdx.x; i < hi; i += 256) {
        uint32_t d = (uint32_t)dst[i];
        uint32_t g = d >> 8;
        uint32_t off = hbase[g] + atomicAdd(&hcur[g], 1u);
        if (off < (uint32_t)gcap)
            groupBuf[(size_t)g * gcap + off] = (uint32_t)src[i] | ((d & 255u) << 20);
    }
}

// Pass 2: scatter into PAIR-INTERLEAVED bucket:
//   node pair p = node>>1 owns slots [p*128, p*128+128);
//   edge #pos of node lands at p*128 + 2*pos + (node&1).
__global__ __launch_bounds__(256) void k_bin2(
    const uint32_t* __restrict__ groupBuf, const uint32_t* __restrict__ gCur,
    uint32_t* __restrict__ bucket, uint32_t* __restrict__ cnt,
    int N, int gcap)
{
    __shared__ uint32_t ncur[256];
    int g = blockIdx.x;
    ncur[threadIdx.x] = 0;
    __syncthreads();
    uint32_t m = gCur[g]; if (m > (uint32_t)gcap) m = gcap;
    int nodebase = g << 8;
    const uint32_t* buf = groupBuf + (size_t)g * gcap;
    for (uint32_t i = threadIdx.x; i < m; i += 256) {
        uint32_t v = buf[i];
        uint32_t nl = v >> 20;
        uint32_t s = v & 0xFFFFFu;
        uint32_t pos = atomicAdd(&ncur[nl], 1u);   // LDS atomic
        if (pos < CAP) {
            uint32_t node = (uint32_t)nodebase + nl;
            bucket[(size_t)(node >> 1) * 128 + 2 * pos + (node & 1)] = s;
        }
    }
    __syncthreads();
    int node = nodebase + threadIdx.x;
    if (node < N) cnt[node] = ncur[threadIdx.x];
}

// ---------------- feature cast f32 -> bf16 (once per call) ----------------

__global__ void k_cast(const float* __restrict__ in, uint32_t* __restrict__ out, int n4) {
    int i = blockIdx.x * blockDim.x + threadIdx.x;
    int stride = gridDim.x * blockDim.x;
    const float4* in4 = (const float4*)in;
    uint2* out2 = (uint2*)out;
    for (; i < n4; i += stride) {
        float4 v = in4[i];
        uint2 r;
        r.x = pack2bf(v.x, v.y);
        r.y = pack2bf(v.z, v.w);
        out2[i] = r;
    }
}

// ---------------- weight transpose f32 -> bf16 (once per call) ----------------

__global__ void k_transpose3(const float* __restrict__ w0, const float* __restrict__ w1,
                             const float* __restrict__ w2, u16* __restrict__ t0,
                             u16* __restrict__ t1, u16* __restrict__ t2) {
    const float* w = blockIdx.x == 0 ? w0 : (blockIdx.x == 1 ? w1 : w2);
    u16* o = blockIdx.x == 0 ? t0 : (blockIdx.x == 1 ? t1 : t2);
    for (int idx = threadIdx.x; idx < DIM * DIM; idx += blockDim.x) {
        int r = idx >> 7, c = idx & 127;
        o[c * DIM + r] = f2bf(w[idx]);
    }
}

// ---------------- gather (segment_sum pull) + LayerNorm fused ----------------
// One wave per NODE PAIR; lane handles dims {2l, 2l+1}; f32 accumulation.
// Pair-interleaved bucket region -> merged stream: slot parity = node (compile-time
// in the unrolled loop). Up to ~32 independent row loads in flight per wave.

__global__ __launch_bounds__(256) void k_gather_ln(
    const uint32_t* __restrict__ xin, const uint32_t* __restrict__ cnt,
    const uint32_t* __restrict__ bucket,
    const int* __restrict__ src, const int* __restrict__ dst,
    const float* __restrict__ gamma, const float* __restrict__ beta,
    uint32_t* __restrict__ h, int N, int E)
{
    int w = threadIdx.x >> 6, l = threadIdx.x & 63;
    int p = blockIdx.x * 4 + w;          // pair index
    int nodeA = 2 * p, nodeB = 2 * p + 1;
    if (nodeA >= N) return;
    bool hasB = nodeB < N;
    uint32_t cA = cnt[nodeA];
    uint32_t cB = hasB ? cnt[nodeB] : 0u;
    float a0 = 0.f, a1 = 0.f, b0 = 0.f, b1 = 0.f;

    if (__builtin_expect(cA > CAP || cB > CAP, 0)) {
        // overflow fallback: raw edge scan for both nodes (never in practice)
        for (int e = 0; e < E; ++e) {
            int d = dst[e];
            if (d == nodeA) { uint32_t v = xin[(size_t)src[e] * 64 + l]; a0 += bflo(v); a1 += bfhi(v); }
            else if (d == nodeB) { uint32_t v = xin[(size_t)src[e] * 64 + l]; b0 += bflo(v); b1 += bfhi(v); }
        }
    } else {
        const uint32_t* reg = bucket + (size_t)p * 128;
        uint32_t cmin = cA < cB ? cA : cB;
        uint32_t J = 2 * cmin;
        uint32_t j = 0;
        // full 32-wide merged batches
        for (; j + 32 <= J; j += 32) {
            uint32_t s[32];
#pragma unroll
            for (int i = 0; i < 32; ++i) s[i] = reg[j + i];
            uint32_t v[32];
#pragma unroll
            for (int i = 0; i < 32; ++i) v[i] = xin[(size_t)s[i] * 64 + l];
#pragma unroll
            for (int i = 0; i < 32; ++i) {
                if (i & 1) { b0 += bflo(v[i]); b1 += bfhi(v[i]); }
                else       { a0 += bflo(v[i]); a1 += bfhi(v[i]); }
            }
        }
        // predicated merged tail (n < 32, wave-uniform)
        {
            uint32_t n = J - j;
            uint32_t v[32];
#pragma unroll
            for (int i = 0; i < 32; ++i) v[i] = ((uint32_t)i < n) ? xin[(size_t)reg[j + i] * 64 + l] : 0u;
#pragma unroll
            for (int i = 0; i < 32; ++i) {
                if (i & 1) { b0 += bflo(v[i]); b1 += bfhi(v[i]); }
                else       { a0 += bflo(v[i]); a1 += bfhi(v[i]); }
            }
        }
        // longer-node drain: entries cmin..cL-1 at stride-2 slots
        uint32_t cL = cA > cB ? cA : cB;
        if (cL > cmin) {
            uint32_t par = (cB > cA) ? 1u : 0u;
            uint32_t n = cL - cmin;
            float t0 = 0.f, t1 = 0.f;
            for (uint32_t t = 0; t < n; t += 16) {
                uint32_t nn2 = n - t; if (nn2 > 16u) nn2 = 16u;
                uint32_t v[16];
#pragma unroll
                for (int i = 0; i < 16; ++i)
                    v[i] = ((uint32_t)i < nn2) ? xin[(size_t)reg[2 * (cmin + t + i) + par] * 64 + l] : 0u;
#pragma unroll
                for (int i = 0; i < 16; ++i) { t0 += bflo(v[i]); t1 += bfhi(v[i]); }
            }
            if (par) { b0 += t0; b1 += t1; } else { a0 += t0; a1 += t1; }
        }
    }

    float gg0 = gamma[2 * l], gg1 = gamma[2 * l + 1];
    float bb0 = beta[2 * l],  bb1 = beta[2 * l + 1];

    // LN for node A
    {
        float sum = a0 + a1, sq = a0 * a0 + a1 * a1;
        for (int off = 32; off; off >>= 1) {
            sum += __shfl_xor(sum, off, 64);
            sq  += __shfl_xor(sq,  off, 64);
        }
        float mean = sum * (1.f / 128.f);
        float var  = sq * (1.f / 128.f) - mean * mean;
        float rs   = rsqrtf(var + 1e-5f);
        float h0 = (a0 - mean) * rs * gg0 + bb0;
        float h1 = (a1 - mean) * rs * gg1 + bb1;
        h[(size_t)nodeA * 64 + l] = pack2bf(h0, h1);
    }
    // LN for node B
    if (hasB) {
        float sum = b0 + b1, sq = b0 * b0 + b1 * b1;
        for (int off = 32; off; off >>= 1) {
            sum += __shfl_xor(sum, off, 64);
            sq  += __shfl_xor(sq,  off, 64);
        }
        float mean = sum * (1.f / 128.f);
        float var  = sq * (1.f / 128.f) - mean * mean;
        float rs   = rsqrtf(var + 1e-5f);
        float h0 = (b0 - mean) * rs * gg0 + bb0;
        float h1 = (b1 - mean) * rs * gg1 + bb1;
        h[(size_t)nodeB * 64 + l] = pack2bf(h0, h1);
    }
}

// ---------------- persistent GEMM: out = relu?(h @ W + b) via MFMA ----------------
// Grid-stride over 32-row tiles; B-fragments + bias hoisted (loaded once per block).
// wt is W transposed (bf16): wt[col*128 + k].

template <int RELU, int OUTF32>
__global__ __launch_bounds__(256) void k_gemm(
    const u16* __restrict__ h, const u16* __restrict__ wt,
    const float* __restrict__ bias, void* __restrict__ outp, int N)
{
    int w = threadIdx.x >> 6, l = threadIdx.x & 63;
    int colbase = (w >> 1) * 64;
    int lr = l & 15, lg = l >> 4;

    short8 bfrag[4][4];
    float bv[4];
#pragma unroll
    for (int ct = 0; ct < 4; ++ct) {
        bv[ct] = bias[colbase + ct * 16 + lr];
#pragma unroll
        for (int kc = 0; kc < 4; ++kc)
            bfrag[ct][kc] = *(const short8*)(wt + (size_t)(colbase + ct * 16 + lr) * DIM + kc * 32 + lg * 8);
    }

    int ntiles = (N + 31) / 32;
    for (int t = blockIdx.x; t < ntiles; t += gridDim.x) {
        int row0 = t * 32 + 16 * (w & 1);
        int ar = row0 + lr;
        if (ar > N - 1) ar = N - 1;

        short8 afrag[4];
#pragma unroll
        for (int kc = 0; kc < 4; ++kc)
            afrag[kc] = *(const short8*)(h + (size_t)ar * DIM + kc * 32 + lg * 8);

#pragma unroll
        for (int ct = 0; ct < 4; ++ct) {
            f32x4 a = {0.f, 0.f, 0.f, 0.f};
#pragma unroll
            for (int kc = 0; kc < 4; ++kc)
                a = __builtin_amdgcn_mfma_f32_16x16x32_bf16(afrag[kc], bfrag[ct][kc], a, 0, 0, 0);
            int col = colbase + ct * 16 + lr;
#pragma unroll
            for (int j = 0; j < 4; ++j) {
                int row = row0 + lg * 4 + j;
                float v = a[j] + bv[ct];
                if (RELU) v = fmaxf(v, 0.f);
                if (row < N) {
                    if (OUTF32) ((float*)outp)[(size_t)row * DIM + col] = v;
                    else        ((u16*)outp)[(size_t)row * DIM + col] = f2bf(v);
                }
            }
        }
    }
}

// ---------------- launch ----------------

extern "C" void kernel_launch(void* const* d_in, const int* in_sizes, int n_in,
                              void* d_out, int out_size, void* d_ws, size_t ws_size,
                              hipStream_t stream) {
    const float* feat = (const float*)d_in[0];
    const int* src  = (const int*)d_in[1];
    const int* dst  = (const int*)d_in[2];
    const float* g1 = (const float*)d_in[3],  *be1 = (const float*)d_in[4];
    const float* W1 = (const float*)d_in[5],  *b1  = (const float*)d_in[6];
    const float* g2 = (const float*)d_in[7],  *be2 = (const float*)d_in[8];
    const float* W2 = (const float*)d_in[9],  *b2  = (const float*)d_in[10];
    const float* g3 = (const float*)d_in[11], *be3 = (const float*)d_in[12];
    const float* W3 = (const float*)d_in[13], *b3  = (const float*)d_in[14];

    int N = in_sizes[0] / DIM;
    int E = in_sizes[1];
    float* out = (float*)d_out;

    int ngrp = (N + 255) >> 8;                 // 391 for N=100000 (max 512)
    int gcap = (E / (ngrp > 0 ? ngrp : 1)) * 3 / 2 + 1024;
    int npair = (N + 1) / 2;

    char* ws = (char*)d_ws;
    auto alloc = [&](size_t bytes) {
        char* p = ws;
        ws += (bytes + 255) & ~(size_t)255;
        return p;
    };
    uint32_t* gCur     = (uint32_t*)alloc((size_t)ngrp * 4);
    uint32_t* groupBuf = (uint32_t*)alloc((size_t)ngrp * gcap * 4);
    uint32_t* cnt      = (uint32_t*)alloc((size_t)N * 4);
    uint32_t* bucket   = (uint32_t*)alloc((size_t)npair * 128 * 4);  // pair-interleaved
    u16* wt1 = (u16*)alloc(DIM * DIM * 2);
    u16* wt2 = (u16*)alloc(DIM * DIM * 2);
    u16* wt3 = (u16*)alloc(DIM * DIM * 2);
    uint32_t* X0 = (uint32_t*)alloc((size_t)N * 64 * 4);  // bf16-packed features
    uint32_t* X1 = (uint32_t*)alloc((size_t)N * 64 * 4);
    uint32_t* X2 = (uint32_t*)alloc((size_t)N * 64 * 4);
    uint32_t* H  = (uint32_t*)alloc((size_t)N * 64 * 4);  // LN output (gemm input)

    hipMemsetAsync(gCur, 0, (size_t)ngrp * 4, stream);
    k_bin1<<<256, 256, 0, stream>>>(src, dst, gCur, groupBuf, E, ngrp, gcap);
    k_bin2<<<ngrp, 256, 0, stream>>>(groupBuf, gCur, bucket, cnt, N, gcap);
    k_transpose3<<<3, 256, 0, stream>>>(W1, W2, W3, wt1, wt2, wt3);
    k_cast<<<1024, 256, 0, stream>>>(feat, X0, N * 32);

    int gblocks = (npair + 3) / 4;

    k_gather_ln<<<gblocks, 256, 0, stream>>>(X0, cnt, bucket, src, dst, g1, be1, H, N, E);
    k_gemm<1, 0><<<512, 256, 0, stream>>>((const u16*)H, wt1, b1, X1, N);
    k_gather_ln<<<gblocks, 256, 0, stream>>>(X1, cnt, bucket, src, dst, g2, be2, H, N, E);
    k_gemm<1, 0><<<512, 256, 0, stream>>>((const u16*)H, wt2, b2, X2, N);
    k_gather_ln<<<gblocks, 256, 0, stream>>>(X2, cnt, bucket, src, dst, g3, be3, H, N, E);
    k_gemm<0, 1><<<512, 256, 0, stream>>>((const u16*)H, wt3, b3, out, N);
}

// Round 10
// 359.359 us; speedup vs baseline: 1.6848x; 1.6848x over previous
//
#include <hip/hip_runtime.h>
#include <hip/hip_bf16.h>
#include <stdint.h>

typedef unsigned short u16;
typedef __attribute__((ext_vector_type(8))) short short8;
typedef __attribute__((ext_vector_type(4))) float f32x4;

#define DIM 128
#define CAP 64   // per-node bucket capacity; deg ~ Poisson(16), P(deg>=64) ~ 2e-18/node

__device__ __forceinline__ float bflo(uint32_t v) {
    uint32_t b = v << 16;
    float f; __builtin_memcpy(&f, &b, 4); return f;
}
__device__ __forceinline__ float bfhi(uint32_t v) {
    uint32_t b = v & 0xffff0000u;
    float f; __builtin_memcpy(&f, &b, 4); return f;
}
__device__ __forceinline__ u16 f2bf(float f) {
    uint32_t x; __builtin_memcpy(&x, &f, 4);
    uint32_t r = (x + 0x7fffu + ((x >> 16) & 1u)) >> 16;
    return (u16)r;
}
__device__ __forceinline__ uint32_t pack2bf(float a, float b) {
    return (uint32_t)f2bf(a) | ((uint32_t)f2bf(b) << 16);
}

// ---------------- sort-based CSR build (no per-edge global atomics) ----------------

__global__ __launch_bounds__(256) void k_bin1(
    const int* __restrict__ src, const int* __restrict__ dst,
    uint32_t* __restrict__ gCur, uint32_t* __restrict__ groupBuf,
    int E, int ngrp, int gcap)
{
    __shared__ uint32_t hcnt[512];
    __shared__ uint32_t hbase[512];
    __shared__ uint32_t hcur[512];
    int nb = gridDim.x;
    int per = (E + nb - 1) / nb;
    int lo = blockIdx.x * per;
    int hi = lo + per; if (hi > E) hi = E;

    for (int t = threadIdx.x; t < ngrp; t += 256) { hcnt[t] = 0; hcur[t] = 0; }
    __syncthreads();

    for (int i = lo + threadIdx.x; i < hi; i += 256)
        atomicAdd(&hcnt[((uint32_t)dst[i]) >> 8], 1u);
    __syncthreads();

    int rot = (blockIdx.x * 37) % (ngrp > 0 ? ngrp : 1);
    for (int k = threadIdx.x; k < ngrp; k += 256) {
        int t = k + rot; if (t >= ngrp) t -= ngrp;
        uint32_t c = hcnt[t];
        hbase[t] = c ? atomicAdd(&gCur[t], c) : 0u;
    }
    __syncthreads();

    for (int i = lo + threadIdx.x; i < hi; i += 256) {
        uint32_t d = (uint32_t)dst[i];
        uint32_t g = d >> 8;
        uint32_t off = hbase[g] + atomicAdd(&hcur[g], 1u);
        if (off < (uint32_t)gcap)
            groupBuf[(size_t)g * gcap + off] = (uint32_t)src[i] | ((d & 255u) << 20);
    }
}

__global__ __launch_bounds__(256) void k_bin2(
    const uint32_t* __restrict__ groupBuf, const uint32_t* __restrict__ gCur,
    uint32_t* __restrict__ bucket, uint32_t* __restrict__ cnt,
    int N, int gcap)
{
    __shared__ uint32_t ncur[256];
    int g = blockIdx.x;
    ncur[threadIdx.x] = 0;
    __syncthreads();
    uint32_t m = gCur[g]; if (m > (uint32_t)gcap) m = gcap;
    int nodebase = g << 8;
    const uint32_t* buf = groupBuf + (size_t)g * gcap;
    for (uint32_t i = threadIdx.x; i < m; i += 256) {
        uint32_t v = buf[i];
        uint32_t nl = v >> 20;
        uint32_t s = v & 0xFFFFFu;
        uint32_t pos = atomicAdd(&ncur[nl], 1u);   // LDS atomic
        if (pos < CAP) bucket[(size_t)(nodebase + (int)nl) * CAP + pos] = s;
    }
    __syncthreads();
    int node = nodebase + threadIdx.x;
    if (node < N) cnt[node] = ncur[threadIdx.x];
}

// ---------------- feature cast f32 -> bf16 (once per call) ----------------

__global__ void k_cast(const float* __restrict__ in, uint32_t* __restrict__ out, int n4) {
    int i = blockIdx.x * blockDim.x + threadIdx.x;
    int stride = gridDim.x * blockDim.x;
    const float4* in4 = (const float4*)in;
    uint2* out2 = (uint2*)out;
    for (; i < n4; i += stride) {
        float4 v = in4[i];
        uint2 r;
        r.x = pack2bf(v.x, v.y);
        r.y = pack2bf(v.z, v.w);
        out2[i] = r;
    }
}

// ---------------- weight transpose f32 -> bf16 (once per call) ----------------

__global__ void k_transpose3(const float* __restrict__ w0, const float* __restrict__ w1,
                             const float* __restrict__ w2, u16* __restrict__ t0,
                             u16* __restrict__ t1, u16* __restrict__ t2) {
    const float* w = blockIdx.x == 0 ? w0 : (blockIdx.x == 1 ? w1 : w2);
    u16* o = blockIdx.x == 0 ? t0 : (blockIdx.x == 1 ? t1 : t2);
    for (int idx = threadIdx.x; idx < DIM * DIM; idx += blockDim.x) {
        int r = idx >> 7, c = idx & 127;
        o[c * DIM + r] = f2bf(w[idx]);
    }
}

// ---------------- gather (segment_sum pull) + LayerNorm fused ----------------
// one wave per node; lane handles dims {2l, 2l+1}; f32 accumulation.
// ILP: batch 16 edges -> 16 independent 256B row loads in flight. (r6-proven: 80us)

__global__ __launch_bounds__(256) void k_gather_ln(
    const uint32_t* __restrict__ xin, const uint32_t* __restrict__ cnt,
    const uint32_t* __restrict__ bucket,
    const int* __restrict__ src, const int* __restrict__ dst,
    const float* __restrict__ gamma, const float* __restrict__ beta,
    uint32_t* __restrict__ h, int N, int E)
{
    int w = threadIdx.x >> 6, l = threadIdx.x & 63;
    int node = blockIdx.x * 4 + w;
    if (node >= N) return;
    uint32_t c = cnt[node];
    float a0 = 0.f, a1 = 0.f;
    if (__builtin_expect(c > CAP, 0)) {
        // overflow fallback: scan the raw edge list (correct, slow, never hit)
        for (int e = 0; e < E; ++e) {
            if (dst[e] == node) {
                uint32_t v = xin[(size_t)src[e] * 64 + l];
                a0 += bflo(v); a1 += bfhi(v);
            }
        }
    } else {
        const uint32_t* bkt = bucket + (size_t)node * CAP;
        uint32_t e = 0;
        while (e + 16 <= c) {
            uint32_t s[16];
#pragma unroll
            for (int i = 0; i < 16; ++i) s[i] = bkt[e + i];
            uint32_t v[16];
#pragma unroll
            for (int i = 0; i < 16; ++i) v[i] = xin[(size_t)s[i] * 64 + l];
#pragma unroll
            for (int i = 0; i < 16; ++i) { a0 += bflo(v[i]); a1 += bfhi(v[i]); }
            e += 16;
        }
        uint32_t n = c - e;   // 0..15, uniform per wave
        uint32_t v[16];
#pragma unroll
        for (int i = 0; i < 16; ++i) v[i] = (i < n) ? xin[(size_t)bkt[e + i] * 64 + l] : 0u;
#pragma unroll
        for (int i = 0; i < 16; ++i) { a0 += bflo(v[i]); a1 += bfhi(v[i]); }
    }
    float sum = a0 + a1;
    float sq  = a0 * a0 + a1 * a1;
    for (int off = 32; off; off >>= 1) {
        sum += __shfl_xor(sum, off, 64);
        sq  += __shfl_xor(sq,  off, 64);
    }
    float mean = sum * (1.f / 128.f);
    float var  = sq * (1.f / 128.f) - mean * mean;
    float rs   = rsqrtf(var + 1e-5f);
    float g0 = gamma[2 * l], g1 = gamma[2 * l + 1];
    float b0 = beta[2 * l],  b1 = beta[2 * l + 1];
    float h0 = (a0 - mean) * rs * g0 + b0;
    float h1 = (a1 - mean) * rs * g1 + b1;
    h[(size_t)node * 64 + l] = pack2bf(h0, h1);
}

// ---------------- persistent GEMM: out = relu?(h @ W + b) via MFMA ----------------
// Grid-stride over 32-row tiles; B-fragments + bias hoisted (loaded once per block).
// wt is W transposed (bf16): wt[col*128 + k].

template <int RELU, int OUTF32>
__global__ __launch_bounds__(256) void k_gemm(
    const u16* __restrict__ h, const u16* __restrict__ wt,
    const float* __restrict__ bias, void* __restrict__ outp, int N)
{
    int w = threadIdx.x >> 6, l = threadIdx.x & 63;
    int colbase = (w >> 1) * 64;
    int lr = l & 15, lg = l >> 4;

    short8 bfrag[4][4];
    float bv[4];
#pragma unroll
    for (int ct = 0; ct < 4; ++ct) {
        bv[ct] = bias[colbase + ct * 16 + lr];
#pragma unroll
        for (int kc = 0; kc < 4; ++kc)
            bfrag[ct][kc] = *(const short8*)(wt + (size_t)(colbase + ct * 16 + lr) * DIM + kc * 32 + lg * 8);
    }

    int ntiles = (N + 31) / 32;
    for (int t = blockIdx.x; t < ntiles; t += gridDim.x) {
        int row0 = t * 32 + 16 * (w & 1);
        int ar = row0 + lr;
        if (ar > N - 1) ar = N - 1;

        short8 afrag[4];
#pragma unroll
        for (int kc = 0; kc < 4; ++kc)
            afrag[kc] = *(const short8*)(h + (size_t)ar * DIM + kc * 32 + lg * 8);

#pragma unroll
        for (int ct = 0; ct < 4; ++ct) {
            f32x4 a = {0.f, 0.f, 0.f, 0.f};
#pragma unroll
            for (int kc = 0; kc < 4; ++kc)
                a = __builtin_amdgcn_mfma_f32_16x16x32_bf16(afrag[kc], bfrag[ct][kc], a, 0, 0, 0);
            int col = colbase + ct * 16 + lr;
#pragma unroll
            for (int j = 0; j < 4; ++j) {
                int row = row0 + lg * 4 + j;
                float v = a[j] + bv[ct];
                if (RELU) v = fmaxf(v, 0.f);
                if (row < N) {
                    if (OUTF32) ((float*)outp)[(size_t)row * DIM + col] = v;
                    else        ((u16*)outp)[(size_t)row * DIM + col] = f2bf(v);
                }
            }
        }
    }
}

// ---------------- launch ----------------

extern "C" void kernel_launch(void* const* d_in, const int* in_sizes, int n_in,
                              void* d_out, int out_size, void* d_ws, size_t ws_size,
                              hipStream_t stream) {
    const float* feat = (const float*)d_in[0];
    const int* src  = (const int*)d_in[1];
    const int* dst  = (const int*)d_in[2];
    const float* g1 = (const float*)d_in[3],  *be1 = (const float*)d_in[4];
    const float* W1 = (const float*)d_in[5],  *b1  = (const float*)d_in[6];
    const float* g2 = (const float*)d_in[7],  *be2 = (const float*)d_in[8];
    const float* W2 = (const float*)d_in[9],  *b2  = (const float*)d_in[10];
    const float* g3 = (const float*)d_in[11], *be3 = (const float*)d_in[12];
    const float* W3 = (const float*)d_in[13], *b3  = (const float*)d_in[14];

    int N = in_sizes[0] / DIM;
    int E = in_sizes[1];
    float* out = (float*)d_out;

    int ngrp = (N + 255) >> 8;                 // 391 for N=100000 (max 512)
    int gcap = (E / (ngrp > 0 ? ngrp : 1)) * 3 / 2 + 1024;

    char* ws = (char*)d_ws;
    auto alloc = [&](size_t bytes) {
        char* p = ws;
        ws += (bytes + 255) & ~(size_t)255;
        return p;
    };
    uint32_t* gCur     = (uint32_t*)alloc((size_t)ngrp * 4);
    uint32_t* groupBuf = (uint32_t*)alloc((size_t)ngrp * gcap * 4);
    uint32_t* cnt      = (uint32_t*)alloc((size_t)N * 4);
    uint32_t* bucket   = (uint32_t*)alloc((size_t)N * CAP * 4);
    u16* wt1 = (u16*)alloc(DIM * DIM * 2);
    u16* wt2 = (u16*)alloc(DIM * DIM * 2);
    u16* wt3 = (u16*)alloc(DIM * DIM * 2);
    uint32_t* X0 = (uint32_t*)alloc((size_t)N * 64 * 4);  // bf16-packed features
    uint32_t* H  = (uint32_t*)alloc((size_t)N * 64 * 4);  // bf16-packed LN out
    uint32_t* X  = (uint32_t*)alloc((size_t)N * 64 * 4);  // bf16-packed layer out

    hipMemsetAsync(gCur, 0, (size_t)ngrp * 4, stream);
    k_bin1<<<256, 256, 0, stream>>>(src, dst, gCur, groupBuf, E, ngrp, gcap);
    k_bin2<<<ngrp, 256, 0, stream>>>(groupBuf, gCur, bucket, cnt, N, gcap);
    k_transpose3<<<3, 256, 0, stream>>>(W1, W2, W3, wt1, wt2, wt3);
    k_cast<<<1024, 256, 0, stream>>>(feat, X0, N * 32);

    int gblocks = (N + 3) / 4;

    // gather reads X (or X0) and writes H; gemm reads H and writes X — never aliased
    k_gather_ln<<<gblocks, 256, 0, stream>>>(X0, cnt, bucket, src, dst, g1, be1, H, N, E);
    k_gemm<1, 0><<<512, 256, 0, stream>>>((const u16*)H, wt1, b1, X, N);
    k_gather_ln<<<gblocks, 256, 0, stream>>>(X, cnt, bucket, src, dst, g2, be2, H, N, E);
    k_gemm<1, 0><<<512, 256, 0, stream>>>((const u16*)H, wt2, b2, X, N);
    k_gather_ln<<<gblocks, 256, 0, stream>>>(X, cnt, bucket, src, dst, g3, be3, H, N, E);
    k_gemm<0, 1><<<512, 256, 0, stream>>>((const u16*)H, wt3, b3, out, N);
}